// Round 2
// 2363.026 us; speedup vs baseline: 2.1474x; 2.1474x over previous
//
#include <hip/hip_runtime.h>

// Problem constants
constexpr int L = 4, D = 512, H = 8, DFF = 2048, NSEQ = 512, B = 16, C = 3;
constexpr int DH = D / H;          // 64
constexpr int M = B * NSEQ;        // 8192 tokens
constexpr int BND = B * NSEQ * D;  // 4,194,304

typedef short bf16x8 __attribute__((ext_vector_type(8)));
typedef float f32x4 __attribute__((ext_vector_type(4)));

// bf16 helpers (OCP bf16 = top 16 bits of fp32)
__device__ __forceinline__ float blo(unsigned u) { return __uint_as_float(u << 16); }
__device__ __forceinline__ float bhi(unsigned u) { return __uint_as_float(u & 0xffff0000u); }
__device__ __forceinline__ unsigned short f2b(float f) {   // RNE
    unsigned u = __float_as_uint(f);
    u += 0x7fffu + ((u >> 16) & 1u);
    return (unsigned short)(u >> 16);
}
__device__ __forceinline__ void gload_lds16(const void* g, void* l) {
    __builtin_amdgcn_global_load_lds(
        (const __attribute__((address_space(1))) void*)g,
        (__attribute__((address_space(3))) void*)l, 16, 0, 0);
}

__device__ __forceinline__ float block_sum256(float v, float* r4) {
#pragma unroll
    for (int o = 32; o > 0; o >>= 1) v += __shfl_xor(v, o, 64);
    if ((threadIdx.x & 63) == 0) r4[threadIdx.x >> 6] = v;
    __syncthreads();
    return r4[0] + r4[1] + r4[2] + r4[3];
}

// ---------------------------------------------------------------------------
// 0. Weight convert + transpose: in fp32 [K][N] -> out bf16 [N][K]. grid.z = L.
__global__ __launch_bounds__(256) void conv_t_kernel(
    const float* __restrict__ in, unsigned short* __restrict__ out, int K, int N)
{
    __shared__ float t[32][33];
    int n0 = blockIdx.x * 32, k0 = blockIdx.y * 32;
    const float* ip = in + (size_t)blockIdx.z * K * N;
    unsigned short* op = out + (size_t)blockIdx.z * K * N;
    int tx = threadIdx.x & 31, ty = threadIdx.x >> 5;   // 32 x 8
#pragma unroll
    for (int i = 0; i < 4; i++)
        t[ty + i * 8][tx] = ip[(size_t)(k0 + ty + i * 8) * N + n0 + tx];
    __syncthreads();
#pragma unroll
    for (int i = 0; i < 4; i++)
        op[(size_t)(n0 + ty + i * 8) * K + k0 + tx] = f2b(t[tx][ty + i * 8]);
}

// ---------------------------------------------------------------------------
// 1. Embedding * sqrt(D) + sinusoidal PE.  x[b,n,d] fp32.
__global__ __launch_bounds__(256) void embed_pe_kernel(
    const int* __restrict__ src, const float* __restrict__ emb,
    float* __restrict__ x)
{
    int idx = blockIdx.x * 256 + threadIdx.x;   // over B*N*D
    int d = idx & (D - 1);
    int t = idx >> 9;            // b*N + n
    int n = t & (NSEQ - 1);
    int b = t >> 9;
    int tok = src[n * B + b];
    float e = emb[(size_t)tok * D + d] * 22.627416997969522f;  // sqrt(512)
    float div = expf((float)(d & ~1) * -0.01798894603797866f); // -ln(1e4)/512
    float ang = (float)n * div;
    float pe = (d & 1) ? cosf(ang) : sinf(ang);
    x[idx] = e + pe;
}

// ---------------------------------------------------------------------------
// 2. LayerNorm over D=512, one block (256 thr) per row. Optional bf16 output.
template<int BF16OUT>
__global__ __launch_bounds__(256) void ln_kernel(
    const float* __restrict__ in, const float* __restrict__ g,
    const float* __restrict__ bt, void* __restrict__ outv)
{
    __shared__ float ra[4], rb[4];
    int row = blockIdx.x, tid = threadIdx.x;
    const float* p = in + (size_t)row * D;
    float v0 = p[tid], v1 = p[tid + 256];
    float mean = block_sum256(v0 + v1, ra) * (1.0f / D);
    float d0 = v0 - mean, d1 = v1 - mean;
    float var = block_sum256(d0 * d0 + d1 * d1, rb) * (1.0f / D);
    float rstd = rsqrtf(var + 1e-6f);
    float o0 = d0 * rstd * g[tid] + bt[tid];
    float o1 = d1 * rstd * g[tid + 256] + bt[tid + 256];
    if (BF16OUT) {
        unsigned short* o = (unsigned short*)outv + (size_t)row * D;
        o[tid] = f2b(o0); o[tid + 256] = f2b(o1);
    } else {
        float* o = (float*)outv + (size_t)row * D;
        o[tid] = o0; o[tid + 256] = o1;
    }
}

// ---------------------------------------------------------------------------
// 3. bf16 MFMA GEMM (m97 structure): out[M,Ndim] = A[M,K] @ Wt[Ndim,K]^T + bias
//    128x128 tile, BK=32, 4 waves, each wave 64x64 = 4x4 frags of 16x16x32.
//    A, Wt bf16; accumulate fp32. ADD: fp32 +=.  BF16OUT: store bf16.
template<int ADD, int RELU, int BF16OUT>
__global__ __launch_bounds__(256) void mfma_gemm(
    const unsigned short* __restrict__ A,    // [Mrows][Kdim] bf16
    const unsigned short* __restrict__ Wt,   // [Ndim][Kdim] bf16 (pre-transposed)
    const float* __restrict__ bias,          // [Ndim] fp32
    void* __restrict__ outv, int Kdim, int Ndim)
{
    __shared__ __align__(16) unsigned short As[128 * 32];  // [m][k]
    __shared__ __align__(16) unsigned short Bs[128 * 32];  // [n][k]
    int tid = threadIdx.x;
    int wave = tid >> 6, lane = tid & 63;
    int lr = lane & 15, lc = lane >> 4;      // frag row(m/n), k-group
    int m0 = blockIdx.y * 128, n0 = blockIdx.x * 128;
    int wm = (wave >> 1) * 64, wn = (wave & 1) * 64;
    int srow = tid >> 2;                     // staging: row within 64-row chunk
    int scol = (tid & 3) << 3;               // staging: k offset (8 bf16 = 16B)

    const unsigned short* Ab = A + ((size_t)m0 + srow) * Kdim + scol;
    const unsigned short* Bb = Wt + ((size_t)n0 + srow) * Kdim + scol;
    unsigned short* AsW = As + wave * 512;   // wave-uniform LDS dest
    unsigned short* BsW = Bs + wave * 512;

    f32x4 acc[4][4] = {};

    for (int kb = 0; kb < Kdim; kb += 32) {
        gload_lds16(Ab + kb, AsW);                               // rows 0-63
        gload_lds16(Ab + kb + (size_t)64 * Kdim, AsW + 2048);    // rows 64-127
        gload_lds16(Bb + kb, BsW);
        gload_lds16(Bb + kb + (size_t)64 * Kdim, BsW + 2048);
        __syncthreads();   // compiler drains vmcnt(0) before s_barrier

        bf16x8 aF[4], bF[4];
#pragma unroll
        for (int i = 0; i < 4; i++) {
            aF[i] = *reinterpret_cast<const bf16x8*>(&As[(wm + i * 16 + lr) * 32 + lc * 8]);
            bF[i] = *reinterpret_cast<const bf16x8*>(&Bs[(wn + i * 16 + lr) * 32 + lc * 8]);
        }
#pragma unroll
        for (int i = 0; i < 4; i++)
#pragma unroll
            for (int j = 0; j < 4; j++)
                acc[i][j] = __builtin_amdgcn_mfma_f32_16x16x32_bf16(aF[i], bF[j], acc[i][j], 0, 0, 0);
        __syncthreads();
    }

    // epilogue: C row = (lane>>4)*4 + r, col = lane&15  (m89-verified layout)
#pragma unroll
    for (int i = 0; i < 4; i++) {
        int grow = m0 + wm + i * 16 + lc * 4;
#pragma unroll
        for (int j = 0; j < 4; j++) {
            int gcol = n0 + wn + j * 16 + lr;
            float bv = bias[gcol];
#pragma unroll
            for (int r = 0; r < 4; r++) {
                float v = acc[i][j][r] + bv;
                if (RELU) v = fmaxf(v, 0.0f);
                size_t off = (size_t)(grow + r) * Ndim + gcol;
                if (BF16OUT)      ((unsigned short*)outv)[off] = f2b(v);
                else if (ADD)     ((float*)outv)[off] += v;
                else              ((float*)outv)[off] = v;
            }
        }
    }
}

// ---------------------------------------------------------------------------
// 4. Flash-style attention, bf16 in / bf16 out, fp32 core (unchanged math).
__global__ __launch_bounds__(256) void attn_tile_kernel(
    const unsigned short* __restrict__ qg, const unsigned short* __restrict__ kg,
    const unsigned short* __restrict__ vg, const int* __restrict__ lengths,
    unsigned short* __restrict__ ctx)
{
    __shared__ float Qs[64][68];
    __shared__ float U[64][68];     // K^T during S-phase, then P
    __shared__ float Vs[64][64];
    __shared__ float mrow[64], lrow[64], arow[64];
    __shared__ float red[256];

    int tid = threadIdx.x;
    int qt = blockIdx.x, hh = blockIdx.y, b = blockIdx.z;
    int tr = tid >> 4, tc = tid & 15;
    int row = tid >> 2, seg = tid & 3;

    const unsigned short* qbase = qg + ((size_t)(b * NSEQ + qt * 64)) * D + hh * DH;
    const unsigned short* kbase = kg + ((size_t)(b * NSEQ)) * D + hh * DH;
    const unsigned short* vbase = vg + ((size_t)(b * NSEQ)) * D + hh * DH;
    int len = lengths[b];

    // load Q tile (16B loads of 8 bf16), convert to fp32 LDS
#pragma unroll
    for (int it = 0; it < 2; it++) {
        int idx = it * 256 + tid;
        int r = idx >> 3, dg = (idx & 7) << 3;
        uint4 t = *reinterpret_cast<const uint4*>(qbase + (size_t)r * D + dg);
        Qs[r][dg + 0] = blo(t.x); Qs[r][dg + 1] = bhi(t.x);
        Qs[r][dg + 2] = blo(t.y); Qs[r][dg + 3] = bhi(t.y);
        Qs[r][dg + 4] = blo(t.z); Qs[r][dg + 5] = bhi(t.z);
        Qs[r][dg + 6] = blo(t.w); Qs[r][dg + 7] = bhi(t.w);
    }
    if (tid < 64) { mrow[tid] = -INFINITY; lrow[tid] = 0.0f; }

    float o[4][4] = {};

    for (int kt = 0; kt < 8; kt++) {
        __syncthreads();
        // stage K^T and V tiles
#pragma unroll
        for (int it = 0; it < 2; it++) {
            int idx = it * 256 + tid;
            int r = idx >> 3, dg = (idx & 7) << 3;
            uint4 t = *reinterpret_cast<const uint4*>(kbase + (size_t)(kt * 64 + r) * D + dg);
            U[dg + 0][r] = blo(t.x); U[dg + 1][r] = bhi(t.x);
            U[dg + 2][r] = blo(t.y); U[dg + 3][r] = bhi(t.y);
            U[dg + 4][r] = blo(t.z); U[dg + 5][r] = bhi(t.z);
            U[dg + 6][r] = blo(t.w); U[dg + 7][r] = bhi(t.w);
            uint4 tv = *reinterpret_cast<const uint4*>(vbase + (size_t)(kt * 64 + r) * D + dg);
            Vs[r][dg + 0] = blo(tv.x); Vs[r][dg + 1] = bhi(tv.x);
            Vs[r][dg + 2] = blo(tv.y); Vs[r][dg + 3] = bhi(tv.y);
            Vs[r][dg + 4] = blo(tv.z); Vs[r][dg + 5] = bhi(tv.z);
            Vs[r][dg + 6] = blo(tv.w); Vs[r][dg + 7] = bhi(tv.w);
        }
        __syncthreads();

        // S = Q . K^T
        float s[4][4] = {};
#pragma unroll
        for (int kk = 0; kk < 64; kk++) {
            float a0 = Qs[tr * 4 + 0][kk];
            float a1 = Qs[tr * 4 + 1][kk];
            float a2 = Qs[tr * 4 + 2][kk];
            float a3 = Qs[tr * 4 + 3][kk];
            float4 bb = *reinterpret_cast<const float4*>(&U[kk][tc * 4]);
            s[0][0] += a0 * bb.x; s[0][1] += a0 * bb.y; s[0][2] += a0 * bb.z; s[0][3] += a0 * bb.w;
            s[1][0] += a1 * bb.x; s[1][1] += a1 * bb.y; s[1][2] += a1 * bb.z; s[1][3] += a1 * bb.w;
            s[2][0] += a2 * bb.x; s[2][1] += a2 * bb.y; s[2][2] += a2 * bb.z; s[2][3] += a2 * bb.w;
            s[3][0] += a3 * bb.x; s[3][1] += a3 * bb.y; s[3][2] += a3 * bb.z; s[3][3] += a3 * bb.w;
        }
        __syncthreads();

        // scaled + masked scores -> U
#pragma unroll
        for (int i = 0; i < 4; i++)
#pragma unroll
            for (int j = 0; j < 4; j++) {
                int col = kt * 64 + tc * 4 + j;
                U[tr * 4 + i][tc * 4 + j] = (col < len) ? s[i][j] * 0.125f : -1e9f;
            }
        __syncthreads();

        // online softmax stats
        float tm = -INFINITY;
#pragma unroll
        for (int e = 0; e < 16; e++) tm = fmaxf(tm, U[row][seg * 16 + e]);
        red[tid] = tm;
        __syncthreads();
        if (seg == 0) {
            float t2 = fmaxf(fmaxf(red[tid], red[tid + 1]), fmaxf(red[tid + 2], red[tid + 3]));
            float nm = fmaxf(mrow[row], t2);
            arow[row] = __expf(mrow[row] - nm);
            mrow[row] = nm;
        }
        __syncthreads();
        float nm = mrow[row];
        float ps = 0.0f;
#pragma unroll
        for (int e = 0; e < 16; e++) {
            float p = __expf(U[row][seg * 16 + e] - nm);
            U[row][seg * 16 + e] = p;
            ps += p;
        }
        red[tid] = ps;
        __syncthreads();
        if (seg == 0)
            lrow[row] = lrow[row] * arow[row] + red[tid] + red[tid + 1] + red[tid + 2] + red[tid + 3];

        // rescale O, then O += P.V
#pragma unroll
        for (int i = 0; i < 4; i++) {
            float a = arow[tr * 4 + i];
#pragma unroll
            for (int j = 0; j < 4; j++) o[i][j] *= a;
        }
#pragma unroll
        for (int kk = 0; kk < 64; kk++) {
            float a0 = U[tr * 4 + 0][kk];
            float a1 = U[tr * 4 + 1][kk];
            float a2 = U[tr * 4 + 2][kk];
            float a3 = U[tr * 4 + 3][kk];
            float4 bb = *reinterpret_cast<const float4*>(&Vs[kk][tc * 4]);
            o[0][0] += a0 * bb.x; o[0][1] += a0 * bb.y; o[0][2] += a0 * bb.z; o[0][3] += a0 * bb.w;
            o[1][0] += a1 * bb.x; o[1][1] += a1 * bb.y; o[1][2] += a1 * bb.z; o[1][3] += a1 * bb.w;
            o[2][0] += a2 * bb.x; o[2][1] += a2 * bb.y; o[2][2] += a2 * bb.z; o[2][3] += a2 * bb.w;
            o[3][0] += a3 * bb.x; o[3][1] += a3 * bb.y; o[3][2] += a3 * bb.z; o[3][3] += a3 * bb.w;
        }
    }
    __syncthreads();

    unsigned short* obase = ctx + ((size_t)(b * NSEQ + qt * 64)) * D + hh * DH;
#pragma unroll
    for (int i = 0; i < 4; i++) {
        float inv = 1.0f / lrow[tr * 4 + i];
        ushort4 st;
        st.x = f2b(o[i][0] * inv); st.y = f2b(o[i][1] * inv);
        st.z = f2b(o[i][2] * inv); st.w = f2b(o[i][3] * inv);
        *reinterpret_cast<ushort4*>(obase + (size_t)(tr * 4 + i) * D + tc * 4) = st;
    }
}

// ---------------------------------------------------------------------------
// 5. Final LN output (fp32) -> attn_res [N,B,D]
__global__ __launch_bounds__(256) void store_attnres(
    const float* __restrict__ hf, float* __restrict__ out)
{
    int idx = blockIdx.x * 256 + threadIdx.x;
    int d  = idx & (D - 1);
    int nb = idx >> 9;      // n*B + b
    int b  = nb & (B - 1);
    int n  = nb >> 4;
    out[idx] = hf[((size_t)(b * NSEQ + n)) * D + d];
}

// ---------------------------------------------------------------------------
// 6. la = hf @ inf_W[:D], lb = hf @ inf_W[D:]. One block per token, shfl reduce.
__global__ __launch_bounds__(256) void lalb_kernel(
    const float* __restrict__ hf, const float* __restrict__ infW,
    float* __restrict__ la, float* __restrict__ lb)
{
    __shared__ float r24[24];
    int t = blockIdx.x, tid = threadIdx.x;
    const float* p = hf + (size_t)t * D;
    float x0 = p[tid], x1 = p[tid + 256];
    float s[6];
#pragma unroll
    for (int c = 0; c < 3; c++) {
        s[c]     = x0 * infW[(size_t)tid * C + c]         + x1 * infW[(size_t)(tid + 256) * C + c];
        s[3 + c] = x0 * infW[(size_t)(tid + 512) * C + c] + x1 * infW[(size_t)(tid + 768) * C + c];
    }
#pragma unroll
    for (int c = 0; c < 6; c++)
#pragma unroll
        for (int o = 32; o > 0; o >>= 1) s[c] += __shfl_xor(s[c], o, 64);
    if ((tid & 63) == 0) {
#pragma unroll
        for (int c = 0; c < 6; c++) r24[c * 4 + (tid >> 6)] = s[c];
    }
    __syncthreads();
    if (tid < 6) {
        float v = r24[tid * 4] + r24[tid * 4 + 1] + r24[tid * 4 + 2] + r24[tid * 4 + 3];
        if (tid < 3) la[(size_t)t * C + tid] = v;
        else         lb[(size_t)t * C + tid - 3] = v;
    }
}

// ---------------------------------------------------------------------------
// 7. logits + log_softmax over C=3; out at [(i*N+j)*B + b]*C + c
__global__ __launch_bounds__(256) void logits_kernel(
    const float* __restrict__ la, const float* __restrict__ lb,
    float* __restrict__ out)
{
    int idx = blockIdx.x * 256 + threadIdx.x;  // over N*N*B
    int b  = idx & (B - 1);
    int ij = idx >> 4;
    int j  = ij & (NSEQ - 1);
    int i  = ij >> 9;
    const float* pa = la + ((size_t)(b * NSEQ + i)) * C;
    const float* pb = lb + ((size_t)(b * NSEQ + j)) * C;
    float l0 = pa[0] + pb[0];
    float l1 = pa[1] + pb[1];
    float l2 = pa[2] + pb[2];
    float m = fmaxf(l0, fmaxf(l1, l2));
    float lse = m + logf(__expf(l0 - m) + __expf(l1 - m) + __expf(l2 - m));
    out[(size_t)idx * 3 + 0] = l0 - lse;
    out[(size_t)idx * 3 + 1] = l1 - lse;
    out[(size_t)idx * 3 + 2] = l2 - lse;
}

// ---------------------------------------------------------------------------
extern "C" void kernel_launch(void* const* d_in, const int* in_sizes, int n_in,
                              void* d_out, int out_size, void* d_ws, size_t ws_size,
                              hipStream_t stream)
{
    const int*   src     = (const int*)  d_in[0];
    const int*   lengths = (const int*)  d_in[1];
    const float* emb     = (const float*)d_in[2];
    const float* ln1_g   = (const float*)d_in[3];
    const float* ln1_b   = (const float*)d_in[4];
    const float* Wq      = (const float*)d_in[5];
    const float* bq      = (const float*)d_in[6];
    const float* Wk      = (const float*)d_in[7];
    const float* bk      = (const float*)d_in[8];
    const float* Wv      = (const float*)d_in[9];
    const float* bv      = (const float*)d_in[10];
    const float* Wo      = (const float*)d_in[11];
    const float* bo      = (const float*)d_in[12];
    const float* ln2_g   = (const float*)d_in[13];
    const float* ln2_b   = (const float*)d_in[14];
    const float* W1      = (const float*)d_in[15];
    const float* b1      = (const float*)d_in[16];
    const float* W2      = (const float*)d_in[17];
    const float* b2      = (const float*)d_in[18];
    const float* lnf_g   = (const float*)d_in[19];
    const float* lnf_b   = (const float*)d_in[20];
    const float* infW    = (const float*)d_in[21];

    // Workspace layout (exactly 5*BND*4 = 83,886,080 bytes):
    //   x      fp32  [M][D]          16,777,216 B
    //   h      bf16  [M][D]           8,388,608 B
    //   wts    bf16  transposed wts  25,165,824 B
    //   big    union:
    //     qkv  bf16  3x[M][D]        25,165,824 B
    //     ffh  bf16  [M][DFF]        33,554,432 B
    //     hf   fp32  [M][D] + la/lb  ~17 MB
    char* wsb = (char*)d_ws;
    float*          x   = (float*)wsb;
    unsigned short* h   = (unsigned short*)(wsb + (size_t)BND * 4);
    unsigned short* wts = (unsigned short*)(wsb + (size_t)BND * 4 + (size_t)BND * 2);
    char*           big = wsb + (size_t)BND * 4 + (size_t)BND * 2 + 25165824;

    unsigned short* qbm = (unsigned short*)big;
    unsigned short* kbm = qbm + (size_t)M * D;
    unsigned short* vbm = kbm + (size_t)M * D;
    unsigned short* ffh = (unsigned short*)big;
    float*          hf  = (float*)big;
    float*          la  = hf + BND;
    float*          lb  = la + (size_t)M * C;

    unsigned short* WQt = wts;
    unsigned short* WKt = WQt + (size_t)L * D * D;
    unsigned short* WVt = WKt + (size_t)L * D * D;
    unsigned short* WOt = WVt + (size_t)L * D * D;
    unsigned short* W1t = WOt + (size_t)L * D * D;    // [L][DFF][D]
    unsigned short* W2t = W1t + (size_t)L * D * DFF;  // [L][D][DFF]

    dim3 blk(256);

    // weight convert+transpose (per launch; ~30 us total)
    conv_t_kernel<<<dim3(D / 32, D / 32, L), blk, 0, stream>>>(Wq, WQt, D, D);
    conv_t_kernel<<<dim3(D / 32, D / 32, L), blk, 0, stream>>>(Wk, WKt, D, D);
    conv_t_kernel<<<dim3(D / 32, D / 32, L), blk, 0, stream>>>(Wv, WVt, D, D);
    conv_t_kernel<<<dim3(D / 32, D / 32, L), blk, 0, stream>>>(Wo, WOt, D, D);
    conv_t_kernel<<<dim3(DFF / 32, D / 32, L), blk, 0, stream>>>(W1, W1t, D, DFF);
    conv_t_kernel<<<dim3(D / 32, DFF / 32, L), blk, 0, stream>>>(W2, W2t, DFF, D);

    embed_pe_kernel<<<BND / 256, blk, 0, stream>>>(src, emb, x);

    dim3 gdd(D / 128, M / 128);     // 4 x 64
    dim3 gdf(DFF / 128, M / 128);   // 16 x 64
    dim3 gattn(NSEQ / 64, H, B);    // 8 x 8 x 16

    for (int l = 0; l < L; l++) {
        size_t bd = (size_t)l * D, wdd = (size_t)l * D * D;
        size_t wdf = (size_t)l * D * DFF, bf1 = (size_t)l * DFF;
        ln_kernel<1><<<M, blk, 0, stream>>>(x, ln1_g + bd, ln1_b + bd, h);
        mfma_gemm<0, 0, 1><<<gdd, blk, 0, stream>>>(h, WQt + wdd, bq + bd, qbm, D, D);
        mfma_gemm<0, 0, 1><<<gdd, blk, 0, stream>>>(h, WKt + wdd, bk + bd, kbm, D, D);
        mfma_gemm<0, 0, 1><<<gdd, blk, 0, stream>>>(h, WVt + wdd, bv + bd, vbm, D, D);
        attn_tile_kernel<<<gattn, blk, 0, stream>>>(qbm, kbm, vbm, lengths, h);
        mfma_gemm<1, 0, 0><<<gdd, blk, 0, stream>>>(h, WOt + wdd, bo + bd, x, D, D);
        ln_kernel<1><<<M, blk, 0, stream>>>(x, ln2_g + bd, ln2_b + bd, h);
        mfma_gemm<0, 1, 1><<<gdf, blk, 0, stream>>>(h, W1t + wdf, b1 + bf1, ffh, D, DFF);
        mfma_gemm<1, 0, 0><<<gdd, blk, 0, stream>>>(ffh, W2t + wdf, b2 + bd, x, DFF, D);
    }

    ln_kernel<0><<<M, blk, 0, stream>>>(x, lnf_g, lnf_b, hf);
    store_attnres<<<(NSEQ * B * D) / 256, blk, 0, stream>>>(hf, (float*)d_out);
    lalb_kernel<<<M, blk, 0, stream>>>(hf, infW, la, lb);
    logits_kernel<<<(NSEQ * NSEQ * B) / 256, blk, 0, stream>>>(
        la, lb, (float*)d_out + (size_t)NSEQ * B * D);
}

// Round 3
// 1133.895 us; speedup vs baseline: 4.4751x; 2.0840x over previous
//
#include <hip/hip_runtime.h>

// Problem constants
constexpr int L = 4, D = 512, H = 8, DFF = 2048, NSEQ = 512, B = 16, C = 3;
constexpr int DH = D / H;          // 64
constexpr int M = B * NSEQ;        // 8192 tokens
constexpr int BND = B * NSEQ * D;  // 4,194,304

typedef short bf16x8 __attribute__((ext_vector_type(8)));
typedef float f32x4 __attribute__((ext_vector_type(4)));

// bf16 helpers (OCP bf16 = top 16 bits of fp32)
__device__ __forceinline__ float blo(unsigned u) { return __uint_as_float(u << 16); }
__device__ __forceinline__ float bhi(unsigned u) { return __uint_as_float(u & 0xffff0000u); }
__device__ __forceinline__ unsigned short f2b(float f) {   // RNE
    unsigned u = __float_as_uint(f);
    u += 0x7fffu + ((u >> 16) & 1u);
    return (unsigned short)(u >> 16);
}
__device__ __forceinline__ void gload_lds16(const void* g, void* l) {
    __builtin_amdgcn_global_load_lds(
        (const __attribute__((address_space(1))) void*)g,
        (__attribute__((address_space(3))) void*)l, 16, 0, 0);
}

__device__ __forceinline__ float block_sum256(float v, float* r4) {
#pragma unroll
    for (int o = 32; o > 0; o >>= 1) v += __shfl_xor(v, o, 64);
    if ((threadIdx.x & 63) == 0) r4[threadIdx.x >> 6] = v;
    __syncthreads();
    return r4[0] + r4[1] + r4[2] + r4[3];
}

// ---------------------------------------------------------------------------
// 0. Weight convert + transpose: in fp32 [K][N] -> out bf16 [N][K]. grid.z = L.
__global__ __launch_bounds__(256) void conv_t_kernel(
    const float* __restrict__ in, unsigned short* __restrict__ out, int K, int N)
{
    __shared__ float t[32][33];
    int n0 = blockIdx.x * 32, k0 = blockIdx.y * 32;
    const float* ip = in + (size_t)blockIdx.z * K * N;
    unsigned short* op = out + (size_t)blockIdx.z * K * N;
    int tx = threadIdx.x & 31, ty = threadIdx.x >> 5;   // 32 x 8
#pragma unroll
    for (int i = 0; i < 4; i++)
        t[ty + i * 8][tx] = ip[(size_t)(k0 + ty + i * 8) * N + n0 + tx];
    __syncthreads();
#pragma unroll
    for (int i = 0; i < 4; i++)
        op[(size_t)(n0 + ty + i * 8) * K + k0 + tx] = f2b(t[tx][ty + i * 8]);
}

// ---------------------------------------------------------------------------
// 1. Embedding * sqrt(D) + sinusoidal PE.  x[b,n,d] fp32.
__global__ __launch_bounds__(256) void embed_pe_kernel(
    const int* __restrict__ src, const float* __restrict__ emb,
    float* __restrict__ x)
{
    int idx = blockIdx.x * 256 + threadIdx.x;   // over B*N*D
    int d = idx & (D - 1);
    int t = idx >> 9;            // b*N + n
    int n = t & (NSEQ - 1);
    int b = t >> 9;
    int tok = src[n * B + b];
    float e = emb[(size_t)tok * D + d] * 22.627416997969522f;  // sqrt(512)
    float div = expf((float)(d & ~1) * -0.01798894603797866f); // -ln(1e4)/512
    float ang = (float)n * div;
    float pe = (d & 1) ? cosf(ang) : sinf(ang);
    x[idx] = e + pe;
}

// ---------------------------------------------------------------------------
// 2. LayerNorm over D=512, one block (256 thr) per row. Optional bf16 output.
template<int BF16OUT>
__global__ __launch_bounds__(256) void ln_kernel(
    const float* __restrict__ in, const float* __restrict__ g,
    const float* __restrict__ bt, void* __restrict__ outv)
{
    __shared__ float ra[4], rb[4];
    int row = blockIdx.x, tid = threadIdx.x;
    const float* p = in + (size_t)row * D;
    float v0 = p[tid], v1 = p[tid + 256];
    float mean = block_sum256(v0 + v1, ra) * (1.0f / D);
    float d0 = v0 - mean, d1 = v1 - mean;
    float var = block_sum256(d0 * d0 + d1 * d1, rb) * (1.0f / D);
    float rstd = rsqrtf(var + 1e-6f);
    float o0 = d0 * rstd * g[tid] + bt[tid];
    float o1 = d1 * rstd * g[tid + 256] + bt[tid + 256];
    if (BF16OUT) {
        unsigned short* o = (unsigned short*)outv + (size_t)row * D;
        o[tid] = f2b(o0); o[tid + 256] = f2b(o1);
    } else {
        float* o = (float*)outv + (size_t)row * D;
        o[tid] = o0; o[tid + 256] = o1;
    }
}

// ---------------------------------------------------------------------------
// 3. bf16 MFMA GEMM (m97 structure): out[M,Ndim] = A[M,K] @ Wt[Ndim,K]^T + bias
//    128x128 tile, BK=32, 4 waves, each wave 64x64 = 4x4 frags of 16x16x32.
//    VTRANS: store output transposed per-batch: out[(b*512 + col)][n] bf16
//    (for the V projection, so attention can read V^T linearly).
template<int ADD, int RELU, int BF16OUT, int VTRANS>
__global__ __launch_bounds__(256) void mfma_gemm(
    const unsigned short* __restrict__ A,    // [Mrows][Kdim] bf16
    const unsigned short* __restrict__ Wt,   // [Ndim][Kdim] bf16 (pre-transposed)
    const float* __restrict__ bias,          // [Ndim] fp32
    void* __restrict__ outv, int Kdim, int Ndim)
{
    __shared__ __align__(16) unsigned short As[128 * 32];  // [m][k]
    __shared__ __align__(16) unsigned short Bs[128 * 32];  // [n][k]
    int tid = threadIdx.x;
    int wave = tid >> 6, lane = tid & 63;
    int lr = lane & 15, lc = lane >> 4;      // frag row(m/n), k-group
    int m0 = blockIdx.y * 128, n0 = blockIdx.x * 128;
    int wm = (wave >> 1) * 64, wn = (wave & 1) * 64;
    int srow = tid >> 2;                     // staging: row within 64-row chunk
    int scol = (tid & 3) << 3;               // staging: k offset (8 bf16 = 16B)

    const unsigned short* Ab = A + ((size_t)m0 + srow) * Kdim + scol;
    const unsigned short* Bb = Wt + ((size_t)n0 + srow) * Kdim + scol;
    unsigned short* AsW = As + wave * 512;   // wave-uniform LDS dest
    unsigned short* BsW = Bs + wave * 512;

    f32x4 acc[4][4] = {};

    for (int kb = 0; kb < Kdim; kb += 32) {
        gload_lds16(Ab + kb, AsW);                               // rows 0-63
        gload_lds16(Ab + kb + (size_t)64 * Kdim, AsW + 2048);    // rows 64-127
        gload_lds16(Bb + kb, BsW);
        gload_lds16(Bb + kb + (size_t)64 * Kdim, BsW + 2048);
        __syncthreads();   // compiler drains vmcnt(0) before s_barrier

        bf16x8 aF[4], bF[4];
#pragma unroll
        for (int i = 0; i < 4; i++) {
            aF[i] = *reinterpret_cast<const bf16x8*>(&As[(wm + i * 16 + lr) * 32 + lc * 8]);
            bF[i] = *reinterpret_cast<const bf16x8*>(&Bs[(wn + i * 16 + lr) * 32 + lc * 8]);
        }
#pragma unroll
        for (int i = 0; i < 4; i++)
#pragma unroll
            for (int j = 0; j < 4; j++)
                acc[i][j] = __builtin_amdgcn_mfma_f32_16x16x32_bf16(aF[i], bF[j], acc[i][j], 0, 0, 0);
        __syncthreads();
    }

    // epilogue: C row = (lane>>4)*4 + r, col = lane&15  (m89-verified layout)
#pragma unroll
    for (int i = 0; i < 4; i++) {
        int grow = m0 + wm + i * 16 + lc * 4;
#pragma unroll
        for (int j = 0; j < 4; j++) {
            int gcol = n0 + wn + j * 16 + lr;
            float bv = bias[gcol];
#pragma unroll
            for (int r = 0; r < 4; r++) {
                float v = acc[i][j][r] + bv;
                if (RELU) v = fmaxf(v, 0.0f);
                if (VTRANS) {
                    int rowg = grow + r;      // token index b*512+n
                    size_t off = ((size_t)((rowg >> 9) << 9) + gcol) * NSEQ + (rowg & (NSEQ - 1));
                    ((unsigned short*)outv)[off] = f2b(v);
                } else {
                    size_t off = (size_t)(grow + r) * Ndim + gcol;
                    if (BF16OUT)      ((unsigned short*)outv)[off] = f2b(v);
                    else if (ADD)     ((float*)outv)[off] += v;
                    else              ((float*)outv)[off] = v;
                }
            }
        }
    }
}

// ---------------------------------------------------------------------------
// 4. Flash attention, MFMA core. bf16 Q/K/V^T in, bf16 ctx out.
//    One block per (b, h, 64-q-tile); 4 waves, each owns a 16-row q-strip.
//    K, V^T staged in XOR-swizzled LDS; P routed through wave-private LDS strip.
__global__ __launch_bounds__(256, 3) void attn_mfma_kernel(
    const unsigned short* __restrict__ qg, const unsigned short* __restrict__ kg,
    const unsigned short* __restrict__ vtg, const int* __restrict__ lengths,
    unsigned short* __restrict__ ctx)
{
    __shared__ __align__(16) unsigned short Ks[64 * 64];  // [kv][d] swizzled
    __shared__ __align__(16) unsigned short Vt[64 * 64];  // [d][kv] swizzled
    __shared__ __align__(16) unsigned short Ps[64 * 64];  // Q staging, then P [q][kv]

    int tid = threadIdx.x;
    int wave = tid >> 6, lane = tid & 63;
    int lr = lane & 15, lc = lane >> 4;
    int qt = blockIdx.x, hh = blockIdx.y, b = blockIdx.z;
    int len = lengths[b];

    const unsigned short* qbase  = qg  + ((size_t)(b * NSEQ + qt * 64)) * D + hh * DH;
    const unsigned short* kbase  = kg  + ((size_t)(b * NSEQ)) * D + hh * DH;
    // V^T: rows = b*512 + hh*64 + d, cols = n (pitch NSEQ)
    const unsigned short* vtbase = vtg + ((size_t)(b * D + hh * DH)) * NSEQ;

    // swizzled byte offset within a [64][64]-bf16 tile (row pitch 128 B)
    auto SW = [](int row, int colbyte) { return row * 128 + (colbyte ^ ((row & 7) << 4)); };

    // ---- stage Q into Ps buffer, grab per-wave A-fragments, then Ps is free
#pragma unroll
    for (int it = 0; it < 2; it++) {
        int c = it * 256 + tid;
        int row = c >> 3, d0 = (c & 7) << 3;
        uint4 t = *reinterpret_cast<const uint4*>(qbase + (size_t)row * D + d0);
        *reinterpret_cast<uint4*>((char*)Ps + SW(row, d0 * 2)) = t;
    }
    __syncthreads();
    bf16x8 aQ[2];
#pragma unroll
    for (int s = 0; s < 2; s++)
        aQ[s] = *reinterpret_cast<const bf16x8*>((char*)Ps + SW(wave * 16 + lr, s * 64 + lc * 16));
    // (no barrier needed: each wave reads/writes only its own 16-row Ps strip)

    f32x4 o[4] = {};
    float mrow[4], lrow[4];
#pragma unroll
    for (int r = 0; r < 4; r++) { mrow[r] = -INFINITY; lrow[r] = 0.0f; }

    for (int kt = 0; kt < 8; kt++) {
        // ---- stage K tile [kv][d] and V^T tile [d][kv], both swizzled
#pragma unroll
        for (int it = 0; it < 2; it++) {
            int c = it * 256 + tid;
            int row = c >> 3, d0 = (c & 7) << 3;
            uint4 t = *reinterpret_cast<const uint4*>(kbase + (size_t)(kt * 64 + row) * D + d0);
            *reinterpret_cast<uint4*>((char*)Ks + SW(row, d0 * 2)) = t;
            uint4 tv = *reinterpret_cast<const uint4*>(vtbase + (size_t)row * NSEQ + kt * 64 + d0);
            *reinterpret_cast<uint4*>((char*)Vt + SW(row, d0 * 2)) = tv;
        }
        __syncthreads();

        // ---- S = Q K^T for this wave's strip (rows 16w..16w+15, cols 64)
        f32x4 sacc[4] = {};
#pragma unroll
        for (int kf = 0; kf < 4; kf++) {
#pragma unroll
            for (int s = 0; s < 2; s++) {
                bf16x8 bK = *reinterpret_cast<const bf16x8*>((char*)Ks + SW(kf * 16 + lr, s * 64 + lc * 16));
                sacc[kf] = __builtin_amdgcn_mfma_f32_16x16x32_bf16(aQ[s], bK, sacc[kf], 0, 0, 0);
            }
        }

        // ---- online softmax; D layout: row=lc*4+r (q_local), col=kf*16+lr (kv)
        float p[4][4], tm[4];
#pragma unroll
        for (int r = 0; r < 4; r++) tm[r] = -INFINITY;
#pragma unroll
        for (int kf = 0; kf < 4; kf++) {
            int col = kt * 64 + kf * 16 + lr;
            bool ok = col < len;
#pragma unroll
            for (int r = 0; r < 4; r++) {
                float sv = ok ? sacc[kf][r] * 0.125f : -1e9f;
                p[kf][r] = sv;
                tm[r] = fmaxf(tm[r], sv);
            }
        }
#pragma unroll
        for (int r = 0; r < 4; r++) {
#pragma unroll
            for (int msk = 1; msk < 16; msk <<= 1)
                tm[r] = fmaxf(tm[r], __shfl_xor(tm[r], msk, 64));
        }
        float alpha[4], ps[4];
#pragma unroll
        for (int r = 0; r < 4; r++) {
            float nm = fmaxf(mrow[r], tm[r]);
            alpha[r] = __expf(mrow[r] - nm);
            mrow[r] = nm;
            ps[r] = 0.0f;
        }
#pragma unroll
        for (int kf = 0; kf < 4; kf++)
#pragma unroll
            for (int r = 0; r < 4; r++) {
                float e = __expf(p[kf][r] - mrow[r]);
                p[kf][r] = e;
                ps[r] += e;
            }
#pragma unroll
        for (int r = 0; r < 4; r++) {
#pragma unroll
            for (int msk = 1; msk < 16; msk <<= 1)
                ps[r] += __shfl_xor(ps[r], msk, 64);
            lrow[r] = lrow[r] * alpha[r] + ps[r];
        }

        // ---- P -> LDS (bf16), wave-private strip
#pragma unroll
        for (int kf = 0; kf < 4; kf++)
#pragma unroll
            for (int r = 0; r < 4; r++)
                *reinterpret_cast<unsigned short*>(
                    (char*)Ps + SW(wave * 16 + lc * 4 + r, (kf * 16 + lr) * 2)) = f2b(p[kf][r]);

        // ---- rescale O by alpha
#pragma unroll
        for (int df = 0; df < 4; df++)
#pragma unroll
            for (int r = 0; r < 4; r++)
                o[df][r] *= alpha[r];

        // ---- O += P V   (A = P rows q, B = Vt rows d)
#pragma unroll
        for (int s = 0; s < 2; s++) {
            bf16x8 pa = *reinterpret_cast<const bf16x8*>((char*)Ps + SW(wave * 16 + lr, s * 64 + lc * 16));
#pragma unroll
            for (int df = 0; df < 4; df++) {
                bf16x8 vb = *reinterpret_cast<const bf16x8*>((char*)Vt + SW(df * 16 + lr, s * 64 + lc * 16));
                o[df] = __builtin_amdgcn_mfma_f32_16x16x32_bf16(pa, vb, o[df], 0, 0, 0);
            }
        }
        __syncthreads();   // all Ks/Vt reads done before next staging
    }

    // ---- epilogue: O row = lc*4+r, col = df*16+lr
    unsigned short* obase = ctx + ((size_t)(b * NSEQ + qt * 64 + wave * 16)) * D + hh * DH;
#pragma unroll
    for (int r = 0; r < 4; r++) {
        float inv = 1.0f / lrow[r];
        int q = lc * 4 + r;
#pragma unroll
        for (int df = 0; df < 4; df++)
            obase[(size_t)q * D + df * 16 + lr] = f2b(o[df][r] * inv);
    }
}

// ---------------------------------------------------------------------------
// 5. Final LN output (fp32) -> attn_res [N,B,D]
__global__ __launch_bounds__(256) void store_attnres(
    const float* __restrict__ hf, float* __restrict__ out)
{
    int idx = blockIdx.x * 256 + threadIdx.x;
    int d  = idx & (D - 1);
    int nb = idx >> 9;      // n*B + b
    int b  = nb & (B - 1);
    int n  = nb >> 4;
    out[idx] = hf[((size_t)(b * NSEQ + n)) * D + d];
}

// ---------------------------------------------------------------------------
// 6. la = hf @ inf_W[:D], lb = hf @ inf_W[D:]. One block per token, shfl reduce.
__global__ __launch_bounds__(256) void lalb_kernel(
    const float* __restrict__ hf, const float* __restrict__ infW,
    float* __restrict__ la, float* __restrict__ lb)
{
    __shared__ float r24[24];
    int t = blockIdx.x, tid = threadIdx.x;
    const float* p = hf + (size_t)t * D;
    float x0 = p[tid], x1 = p[tid + 256];
    float s[6];
#pragma unroll
    for (int c = 0; c < 3; c++) {
        s[c]     = x0 * infW[(size_t)tid * C + c]         + x1 * infW[(size_t)(tid + 256) * C + c];
        s[3 + c] = x0 * infW[(size_t)(tid + 512) * C + c] + x1 * infW[(size_t)(tid + 768) * C + c];
    }
#pragma unroll
    for (int c = 0; c < 6; c++)
#pragma unroll
        for (int o = 32; o > 0; o >>= 1) s[c] += __shfl_xor(s[c], o, 64);
    if ((tid & 63) == 0) {
#pragma unroll
        for (int c = 0; c < 6; c++) r24[c * 4 + (tid >> 6)] = s[c];
    }
    __syncthreads();
    if (tid < 6) {
        float v = r24[tid * 4] + r24[tid * 4 + 1] + r24[tid * 4 + 2] + r24[tid * 4 + 3];
        if (tid < 3) la[(size_t)t * C + tid] = v;
        else         lb[(size_t)t * C + tid - 3] = v;
    }
}

// ---------------------------------------------------------------------------
// 7. logits + log_softmax over C=3; out at [(i*N+j)*B + b]*C + c
__global__ __launch_bounds__(256) void logits_kernel(
    const float* __restrict__ la, const float* __restrict__ lb,
    float* __restrict__ out)
{
    int idx = blockIdx.x * 256 + threadIdx.x;  // over N*N*B
    int b  = idx & (B - 1);
    int ij = idx >> 4;
    int j  = ij & (NSEQ - 1);
    int i  = ij >> 9;
    const float* pa = la + ((size_t)(b * NSEQ + i)) * C;
    const float* pb = lb + ((size_t)(b * NSEQ + j)) * C;
    float l0 = pa[0] + pb[0];
    float l1 = pa[1] + pb[1];
    float l2 = pa[2] + pb[2];
    float m = fmaxf(l0, fmaxf(l1, l2));
    float lse = m + logf(__expf(l0 - m) + __expf(l1 - m) + __expf(l2 - m));
    out[(size_t)idx * 3 + 0] = l0 - lse;
    out[(size_t)idx * 3 + 1] = l1 - lse;
    out[(size_t)idx * 3 + 2] = l2 - lse;
}

// ---------------------------------------------------------------------------
extern "C" void kernel_launch(void* const* d_in, const int* in_sizes, int n_in,
                              void* d_out, int out_size, void* d_ws, size_t ws_size,
                              hipStream_t stream)
{
    const int*   src     = (const int*)  d_in[0];
    const int*   lengths = (const int*)  d_in[1];
    const float* emb     = (const float*)d_in[2];
    const float* ln1_g   = (const float*)d_in[3];
    const float* ln1_b   = (const float*)d_in[4];
    const float* Wq      = (const float*)d_in[5];
    const float* bq      = (const float*)d_in[6];
    const float* Wk      = (const float*)d_in[7];
    const float* bk      = (const float*)d_in[8];
    const float* Wv      = (const float*)d_in[9];
    const float* bv      = (const float*)d_in[10];
    const float* Wo      = (const float*)d_in[11];
    const float* bo      = (const float*)d_in[12];
    const float* ln2_g   = (const float*)d_in[13];
    const float* ln2_b   = (const float*)d_in[14];
    const float* W1      = (const float*)d_in[15];
    const float* b1      = (const float*)d_in[16];
    const float* W2      = (const float*)d_in[17];
    const float* b2      = (const float*)d_in[18];
    const float* lnf_g   = (const float*)d_in[19];
    const float* lnf_b   = (const float*)d_in[20];
    const float* infW    = (const float*)d_in[21];

    // Workspace layout (exactly 5*BND*4 = 83,886,080 bytes):
    //   x      fp32  [M][D]          16,777,216 B
    //   h      bf16  [M][D]           8,388,608 B
    //   wts    bf16  transposed wts  25,165,824 B
    //   big    union:
    //     q/k/vt bf16 3x[M][D]       25,165,824 B  (vt transposed per batch)
    //     ffh  bf16  [M][DFF]        33,554,432 B
    //     hf   fp32  [M][D] + la/lb  ~17 MB
    char* wsb = (char*)d_ws;
    float*          x   = (float*)wsb;
    unsigned short* h   = (unsigned short*)(wsb + (size_t)BND * 4);
    unsigned short* wts = (unsigned short*)(wsb + (size_t)BND * 4 + (size_t)BND * 2);
    char*           big = wsb + (size_t)BND * 4 + (size_t)BND * 2 + 25165824;

    unsigned short* qbm = (unsigned short*)big;
    unsigned short* kbm = qbm + (size_t)M * D;
    unsigned short* vtm = kbm + (size_t)M * D;   // V^T: [b*512 + dcol][n]
    unsigned short* ffh = (unsigned short*)big;
    float*          hf  = (float*)big;
    float*          la  = hf + BND;
    float*          lb  = la + (size_t)M * C;

    unsigned short* WQt = wts;
    unsigned short* WKt = WQt + (size_t)L * D * D;
    unsigned short* WVt = WKt + (size_t)L * D * D;
    unsigned short* WOt = WVt + (size_t)L * D * D;
    unsigned short* W1t = WOt + (size_t)L * D * D;    // [L][DFF][D]
    unsigned short* W2t = W1t + (size_t)L * D * DFF;  // [L][D][DFF]

    dim3 blk(256);

    // weight convert+transpose (per launch; ~30 us total)
    conv_t_kernel<<<dim3(D / 32, D / 32, L), blk, 0, stream>>>(Wq, WQt, D, D);
    conv_t_kernel<<<dim3(D / 32, D / 32, L), blk, 0, stream>>>(Wk, WKt, D, D);
    conv_t_kernel<<<dim3(D / 32, D / 32, L), blk, 0, stream>>>(Wv, WVt, D, D);
    conv_t_kernel<<<dim3(D / 32, D / 32, L), blk, 0, stream>>>(Wo, WOt, D, D);
    conv_t_kernel<<<dim3(DFF / 32, D / 32, L), blk, 0, stream>>>(W1, W1t, D, DFF);
    conv_t_kernel<<<dim3(D / 32, DFF / 32, L), blk, 0, stream>>>(W2, W2t, DFF, D);

    embed_pe_kernel<<<BND / 256, blk, 0, stream>>>(src, emb, x);

    dim3 gdd(D / 128, M / 128);     // 4 x 64
    dim3 gdf(DFF / 128, M / 128);   // 16 x 64
    dim3 gattn(NSEQ / 64, H, B);    // 8 x 8 x 16

    for (int l = 0; l < L; l++) {
        size_t bd = (size_t)l * D, wdd = (size_t)l * D * D;
        size_t wdf = (size_t)l * D * DFF, bf1 = (size_t)l * DFF;
        ln_kernel<1><<<M, blk, 0, stream>>>(x, ln1_g + bd, ln1_b + bd, h);
        mfma_gemm<0, 0, 1, 0><<<gdd, blk, 0, stream>>>(h, WQt + wdd, bq + bd, qbm, D, D);
        mfma_gemm<0, 0, 1, 0><<<gdd, blk, 0, stream>>>(h, WKt + wdd, bk + bd, kbm, D, D);
        mfma_gemm<0, 0, 1, 1><<<gdd, blk, 0, stream>>>(h, WVt + wdd, bv + bd, vtm, D, D);
        attn_mfma_kernel<<<gattn, blk, 0, stream>>>(qbm, kbm, vtm, lengths, h);
        mfma_gemm<1, 0, 0, 0><<<gdd, blk, 0, stream>>>(h, WOt + wdd, bo + bd, x, D, D);
        ln_kernel<1><<<M, blk, 0, stream>>>(x, ln2_g + bd, ln2_b + bd, h);
        mfma_gemm<0, 1, 1, 0><<<gdf, blk, 0, stream>>>(h, W1t + wdf, b1 + bf1, ffh, D, DFF);
        mfma_gemm<1, 0, 0, 0><<<gdd, blk, 0, stream>>>(ffh, W2t + wdf, b2 + bd, x, DFF, D);
    }

    ln_kernel<0><<<M, blk, 0, stream>>>(x, lnf_g, lnf_b, hf);
    store_attnres<<<(NSEQ * B * D) / 256, blk, 0, stream>>>(hf, (float*)d_out);
    lalb_kernel<<<M, blk, 0, stream>>>(hf, infW, la, lb);
    logits_kernel<<<(NSEQ * NSEQ * B) / 256, blk, 0, stream>>>(
        la, lb, (float*)d_out + (size_t)NSEQ * B * D);
}